// Round 9
// baseline (382.592 us; speedup 1.0000x reference)
//
#include <hip/hip_runtime.h>
#include <stdint.h>

// ---------------------------------------------------------------------------
// Social LSTM model, bf16x3 MFMA everywhere.
//   enc:  LSTM(2->64), T=50. 1088 blocks x 4 waves, TWO independent 16-seq
//         groups per block (B-frags shared) -> 2x per-wave ILP to fill
//         exp/rcp latency bubbles, 1 barrier per t for both groups.
//   pool: fused into dec staging (masked max over nenc, batched loads).
//   dec:  LSTMCell(128->128), 30 steps. 256 blocks x 8 waves, 8 seqs/block.
//         B register-resident, loaded once; gates cross waves via LDS.
// Pointwise: shared-rcp sigmoid/tanh algebra; g-gate weights pre-scaled
// by 2 in prep. launch_bounds: enc (256,2) [256-VGPR budget; (256,4)
// spilled in R6]; dec (512,2).
// ---------------------------------------------------------------------------

#define T_SEQ 50
#define PRED_STEPS 30
#define NMAX 16

typedef float v2f __attribute__((ext_vector_type(2)));
typedef float v4f __attribute__((ext_vector_type(4)));
typedef short v8s __attribute__((ext_vector_type(8)));

// ws layout (float offsets)
static constexpr size_t OFF_AEMB  = 0;          // 2048*64
static constexpr size_t OFF_NENC  = 131072;     // 32768*64
static constexpr size_t OFF_PACKA = 2490368;    // 64 KB bf16 B-frags (agent)
static constexpr size_t OFF_PACKN = 2507520;    // 64 KB bf16 B-frags (neigh)
static constexpr size_t OFF_WDP   = 2524672;    // 256 KB dec bf16 B-frags
static constexpr size_t OFF_WDB   = 2590208;    // 512 fused dec bias

__device__ __forceinline__ float frcp(float x) { return __builtin_amdgcn_rcpf(x); }
__device__ __forceinline__ unsigned bf16rne(float f) {
  unsigned u = __float_as_uint(f);
  u += 0x7fff + ((u >> 16) & 1);
  return u >> 16;
}
__device__ __forceinline__ float bf16tof(unsigned h) { return __uint_as_float(h << 16); }
__device__ __forceinline__ v4f mfma16(v8s a, v8s b, v4f c) {
  return __builtin_amdgcn_mfma_f32_16x16x32_bf16(a, b, c, 0, 0, 0);
}

// Shared-rcp LSTM cell update. gv PRE-SCALED by 2: eg = exp(-2*g_true).
__device__ __forceinline__ float cell_update(float iv, float fv, float gv,
                                             float ov, float& cref) {
  float ef = __expf(-fv);
  float ei = __expf(-iv);
  float eg = __expf(-gv);
  float t1 = (1.f + ei) * (1.f + eg);
  float rD = frcp((1.f + ef) * t1);
  float sf = t1 * rD;
  float u  = (1.f - eg) * ((1.f + ef) * rD);
  float cn = fmaf(sf, cref, u);
  cref = cn;
  float eo = __expf(-ov);
  float ec = __expf(fminf(-2.f * cn, 41.5f));
  return (1.f - ec) * frcp((1.f + eo) * (1.f + ec));
}

// ---------------------------------------------------------------------------
// Merged prep. Blocks 0..31: encoder packs. Blocks 32..95: decoder pack.
// g-gate (g==2) weights and bias scaled by 2.
// ---------------------------------------------------------------------------
__global__ void prep_kernel(const float* __restrict__ Whh_a, const float* __restrict__ Whh_n,
                            const float* __restrict__ Wih_d, const float* __restrict__ Whh_d,
                            const float* __restrict__ bih_d, const float* __restrict__ bhh_d,
                            uint4* __restrict__ packA, uint4* __restrict__ packN,
                            uint4* __restrict__ packD, float* __restrict__ bd) {
  if (blockIdx.x < 32) {
    const int which = blockIdx.x >> 4;
    const int idx = (blockIdx.x & 15) * 256 + threadIdx.x;  // 0..4095
    const float* Whh = which ? Whh_n : Whh_a;
    uint4* dst = which ? packN : packA;
    const int lane = idx & 63, c = idx >> 6;
    const int p = c & 1, kh = (c >> 1) & 1, g = (c >> 2) & 3, w = (c >> 4) & 3;
    const float gs = (g == 2) ? 2.f : 1.f;
    const int row = g * 64 + 16 * w + (lane & 15);
    const int kb = kh * 32 + (lane >> 4) * 8;
    unsigned us[8];
#pragma unroll
    for (int e = 0; e < 8; ++e) {
      float W = Whh[row * 64 + kb + e] * gs;
      unsigned hi = bf16rne(W);
      us[e] = p ? bf16rne(W - bf16tof(hi)) : hi;
    }
    uint4 o;
    o.x = us[0] | (us[1] << 16);
    o.y = us[2] | (us[3] << 16);
    o.z = us[4] | (us[5] << 16);
    o.w = us[6] | (us[7] << 16);
    dst[c * 64 + lane] = o;
  } else {
    const int idx = (blockIdx.x - 32) * 256 + threadIdx.x;  // 0..16383
    const int lane = idx & 63, c = idx >> 6;
    const int p = c & 1, kh = (c >> 1) & 3, ut = (c >> 3) & 3, uhf = (c >> 5) & 1, g = (c >> 6) & 3;
    const float gs = (g == 2) ? 2.f : 1.f;
    const int j = uhf * 64 + ut * 16 + (lane & 15);
    const int row = g * 128 + j;
    const int kb = kh * 32 + (lane >> 4) * 8;
    unsigned us[8];
#pragma unroll
    for (int e = 0; e < 8; ++e) {
      float W = (Wih_d[row * 128 + kb + e] + Whh_d[row * 128 + kb + e]) * gs;
      unsigned hi = bf16rne(W);
      us[e] = p ? bf16rne(W - bf16tof(hi)) : hi;
    }
    uint4 o;
    o.x = us[0] | (us[1] << 16);
    o.y = us[2] | (us[3] << 16);
    o.z = us[4] | (us[5] << 16);
    o.w = us[6] | (us[7] << 16);
    packD[c * 64 + lane] = o;
    if (blockIdx.x < 34) {
      int i = (blockIdx.x - 32) * 256 + threadIdx.x;  // 0..511
      float s = ((i >> 7) == 2) ? 2.f : 1.f;
      bd[i] = (bih_d[i] + bhh_d[i]) * s;
    }
  }
}

// ---------------------------------------------------------------------------
// Encoder. Blocks [0,1024) neighbour, [1024,1088) agent; 256 thr = 4 waves;
// 32 seqs/block as two independent 16-seq groups (shared B-frags).
// Per group: ping-pong h planes, halfword base grp*4608 + buf*2304,
// hi [+0,+1152), lo [+1152,+2304), row stride 72 hw. One barrier per t.
// ---------------------------------------------------------------------------
__global__ __launch_bounds__(256, 2) void enc_mfma_kernel(
    const float* __restrict__ xA, const float* __restrict__ xN,
    const v8s* __restrict__ packA, const v8s* __restrict__ packN,
    const float* __restrict__ Wih_a, const float* __restrict__ bih_a, const float* __restrict__ bhh_a,
    const float* __restrict__ Wih_n, const float* __restrict__ bih_n, const float* __restrict__ bhh_n,
    float* __restrict__ outA, float* __restrict__ outN) {
  __shared__ unsigned short hph[9216];  // 2 groups x 2 ping-pong buffers
  __shared__ float xst[3200];           // 2 groups x 16 seqs x 50 t x 2
  const int tid = threadIdx.x, lane = tid & 63, wv = tid >> 6;
  const int nb = blockIdx.x;
  const bool isA = nb >= 1024;
  const float* xsrc = isA ? xA : xN;
  const v8s* pk = isA ? packA : packN;
  const float* Wih = isA ? Wih_a : Wih_n;
  const float* bih = isA ? bih_a : bih_n;
  const float* bhh = isA ? bhh_a : bhh_n;
  float* outp = isA ? outA : outN;
  const int s0 = (isA ? nb - 1024 : nb) * 32;

  // register-resident B fragments: [gate][khalf][hi/lo] -- shared by groups
  v8s B[4][2][2];
#pragma unroll
  for (int g = 0; g < 4; ++g)
#pragma unroll
    for (int kh = 0; kh < 2; ++kh)
#pragma unroll
      for (int p = 0; p < 2; ++p)
        B[g][kh][p] = pk[((((wv * 4 + g) * 2 + kh) * 2 + p) << 6) + lane];

  const int jc = lane & 15, qc = lane >> 4;  // C roles: unit col, seq quad
  float wi0[4], wi1[4], bs[4];
#pragma unroll
  for (int g = 0; g < 4; ++g) {
    const float gs = (g == 2) ? 2.f : 1.f;
    int n = g * 64 + 16 * wv + jc;
    wi0[g] = Wih[n * 2 + 0] * gs;
    wi1[g] = Wih[n * 2 + 1] * gs;
    bs[g] = (bih[n] + bhh[n]) * gs;
  }

  // stage x (3200 floats) + zero all h planes (4608 dwords)
  {
    const float4* xb = (const float4*)(xsrc + (size_t)s0 * 100);
    for (int i = tid; i < 800; i += 256) ((float4*)xst)[i] = xb[i];
    for (int i = tid; i < 4608; i += 256) ((unsigned*)hph)[i] = 0;
  }
  __syncthreads();

  const int ms = lane & 15, ks = lane >> 4;  // A roles: seq row, k-quad
  float cst[2][4] = {{0.f, 0.f, 0.f, 0.f}, {0.f, 0.f, 0.f, 0.f}};
  float h[2][4];

  auto step2 = [&](int t, int rb, int wb) {
    // A fragments, both groups (8 ds_read_b128)
    v8s Ahi[2][2], Alo[2][2];
#pragma unroll
    for (int gp = 0; gp < 2; ++gp)
#pragma unroll
      for (int kh = 0; kh < 2; ++kh) {
        Ahi[gp][kh] = *(const __shared__ v8s*)&hph[gp * 4608 + rb + ms * 72 + kh * 32 + ks * 8];
        Alo[gp][kh] = *(const __shared__ v8s*)&hph[gp * 4608 + rb + 1152 + ms * 72 + kh * 32 + ks * 8];
      }

    // acc init: exact fp32 input projection + bias
    v4f a4[2][4];
#pragma unroll
    for (int gp = 0; gp < 2; ++gp)
#pragma unroll
      for (int r = 0; r < 4; ++r) {
        v2f xv = *(const __shared__ v2f*)&xst[gp * 1600 + (qc * 4 + r) * 100 + 2 * t];
#pragma unroll
        for (int g = 0; g < 4; ++g)
          a4[gp][g][r] = fmaf(wi1[g], xv.y, fmaf(wi0[g], xv.x, bs[g]));
      }

    // h @ Whh^T via bf16x3 MFMA, both groups (48 MFMA)
#pragma unroll
    for (int gp = 0; gp < 2; ++gp)
#pragma unroll
      for (int g = 0; g < 4; ++g)
#pragma unroll
        for (int kh = 0; kh < 2; ++kh) {
          a4[gp][g] = mfma16(Ahi[gp][kh], B[g][kh][0], a4[gp][g]);
          a4[gp][g] = mfma16(Ahi[gp][kh], B[g][kh][1], a4[gp][g]);
          a4[gp][g] = mfma16(Alo[gp][kh], B[g][kh][0], a4[gp][g]);
        }

    // pointwise, 8 independent cells -> deep ILP across exp/rcp chains
#pragma unroll
    for (int gp = 0; gp < 2; ++gp)
#pragma unroll
      for (int r = 0; r < 4; ++r) {
        h[gp][r] = cell_update(a4[gp][0][r], a4[gp][1][r], a4[gp][2][r],
                               a4[gp][3][r], cst[gp][r]);
        unsigned uu = __float_as_uint(h[gp][r]);
        float hif = __uint_as_float(uu & 0xffff0000u);
        float lof = h[gp][r] - hif;
        int ha = gp * 4608 + wb + (qc * 4 + r) * 72 + 16 * wv + jc;
        hph[ha] = (unsigned short)(uu >> 16);
        hph[1152 + ha] = (unsigned short)(__float_as_uint(lof) >> 16);
      }
    __syncthreads();  // single barrier covers both groups
  };

  for (int t2 = 0; t2 < T_SEQ; t2 += 2) {
    step2(t2 + 0, 0, 2304);      // literal bases -> imm LDS offsets
    step2(t2 + 1, 2304, 0);
  }

#pragma unroll
  for (int gp = 0; gp < 2; ++gp)
#pragma unroll
    for (int r = 0; r < 4; ++r)
      outp[(size_t)(s0 + gp * 16 + qc * 4 + r) * 64 + 16 * wv + jc] = h[gp][r];
}

// ---------------------------------------------------------------------------
// Decoder MFMA v3. 256 blocks x 512 thr (8 waves), 8 seqs/block.
// Staging fuses the masked neighbour max-pool (batched 16 loads + mask).
// Wave wv: gate g = wv&3, unit-half uhf = wv>>2 -> 4 col-tiles of 16 units.
// B register-resident (32 v8s = 128 VGPR), loaded ONCE.
// ---------------------------------------------------------------------------
__global__ __launch_bounds__(512, 2) void dec_mfma_kernel(
    const v8s* __restrict__ pkd, const float* __restrict__ bd,
    const float* __restrict__ aemb, const float* __restrict__ nenc,
    const int* __restrict__ cnts, const float* __restrict__ Wpos,
    const float* __restrict__ bpos, float* __restrict__ out) {
  __shared__ unsigned short hph[4352];
  __shared__ float gbuf[4][8][132];
  const int tid = threadIdx.x, lane = tid & 63, wv = tid >> 6;
  const int jc = lane & 15, qc = lane >> 4;
  const int g = wv & 3, uhf = wv >> 2;
  const int s0 = blockIdx.x * 8;

  // register-resident B fragments: [utile][kh][hi/lo]
  v8s B[4][4][2];
#pragma unroll
  for (int ut = 0; ut < 4; ++ut)
#pragma unroll
    for (int kh = 0; kh < 4; ++kh)
#pragma unroll
      for (int p = 0; p < 2; ++p) {
        int c = (g << 6) | (uhf << 5) | (ut << 3) | (kh << 1) | p;
        B[ut][kh][p] = pkd[(c << 6) + lane];
      }
  float bs[4];
#pragma unroll
  for (int ut = 0; ut < 4; ++ut)
    bs[ut] = bd[g * 128 + uhf * 64 + ut * 16 + jc];

  const int u0 = 2 * lane;
  const float wpA0 = Wpos[u0], wpA1 = Wpos[u0 + 1];
  const float wpB0 = Wpos[128 + u0], wpB1 = Wpos[128 + u0 + 1];
  const float bp0 = bpos[0], bp1 = bpos[1];

  // stage h0 rows 0..7 (fused hmax, batched loads) + zero rows 8..15
  for (int i = tid; i < 2048; i += 512) {
    int row = i >> 7, unit = i & 127;
    unsigned hiw = 0, low = 0;
    if (row < 8) {
      float v;
      if (unit < 64) {
        v = aemb[(size_t)(s0 + row) * 64 + unit];
      } else {
        int cnt = cnts[s0 + row];
        float m = -1e30f;
#pragma unroll
        for (int n = 0; n < NMAX; ++n) {
          float val = nenc[((size_t)((s0 + row) * NMAX + n)) * 64 + (unit - 64)];
          m = (n < cnt) ? fmaxf(m, val) : m;
        }
        v = (cnt > 0) ? m : 0.f;
      }
      unsigned u = __float_as_uint(v);
      float hif = __uint_as_float(u & 0xffff0000u);
      float lof = v - hif;
      hiw = u >> 16;
      low = __float_as_uint(lof) >> 16;
    }
    hph[row * 136 + unit] = (unsigned short)hiw;
    hph[2176 + row * 136 + unit] = (unsigned short)low;
  }
  float cA = 0.f, cB = 0.f;
  __syncthreads();

  for (int t = 0; t < PRED_STEPS; ++t) {
    v8s Ahi[4], Alo[4];
#pragma unroll
    for (int kh = 0; kh < 4; ++kh) {
      Ahi[kh] = *(const __shared__ v8s*)&hph[jc * 136 + kh * 32 + qc * 8];
      Alo[kh] = *(const __shared__ v8s*)&hph[2176 + jc * 136 + kh * 32 + qc * 8];
    }

    v4f acc[4];
#pragma unroll
    for (int ut = 0; ut < 4; ++ut)
      acc[ut] = (v4f){bs[ut], bs[ut], bs[ut], bs[ut]};
#pragma unroll
    for (int ut = 0; ut < 4; ++ut)
#pragma unroll
      for (int kh = 0; kh < 4; ++kh) {
        acc[ut] = mfma16(Ahi[kh], B[ut][kh][0], acc[ut]);
        acc[ut] = mfma16(Ahi[kh], B[ut][kh][1], acc[ut]);
        acc[ut] = mfma16(Alo[kh], B[ut][kh][0], acc[ut]);
      }

    // publish gates (rows 0..7 only -> lanes qc<2)
    if (qc < 2) {
#pragma unroll
      for (int ut = 0; ut < 4; ++ut)
#pragma unroll
        for (int r = 0; r < 4; ++r)
          gbuf[g][qc * 4 + r][uhf * 64 + ut * 16 + jc] = acc[ut][r];
    }
    __syncthreads();  // barrier1: gates visible (A-reads complete)

    // cell phase: wave wv <-> seq wv, lane -> units u0,u0+1
    v2f gI = *(const __shared__ v2f*)&gbuf[0][wv][u0];
    v2f gF = *(const __shared__ v2f*)&gbuf[1][wv][u0];
    v2f gG = *(const __shared__ v2f*)&gbuf[2][wv][u0];
    v2f gO = *(const __shared__ v2f*)&gbuf[3][wv][u0];
    float hA = cell_update(gI.x, gF.x, gG.x, gO.x, cA);
    float hB = cell_update(gI.y, gF.y, gG.y, gO.y, cB);

    unsigned uA = __float_as_uint(hA), uB = __float_as_uint(hB);
    float hifA = __uint_as_float(uA & 0xffff0000u);
    float hifB = __uint_as_float(uB & 0xffff0000u);
    unsigned loA = __float_as_uint(hA - hifA) >> 16;
    unsigned loB = __float_as_uint(hB - hifB) >> 16;
    ((unsigned*)hph)[wv * 68 + lane] = (uA >> 16) | (uB & 0xffff0000u);
    ((unsigned*)hph)[1088 + wv * 68 + lane] = loA | (loB << 16);

    float p0 = hA * wpA0 + hB * wpA1;
    float p1 = hA * wpB0 + hB * wpB1;
#pragma unroll
    for (int off = 32; off > 0; off >>= 1) {
      p0 += __shfl_xor(p0, off, 64);
      p1 += __shfl_xor(p1, off, 64);
    }
    if (lane == 0) {
      out[(size_t)(s0 + wv) * (PRED_STEPS * 2) + t * 2 + 0] = p0 + bp0;
      out[(size_t)(s0 + wv) * (PRED_STEPS * 2) + t * 2 + 1] = p1 + bp1;
    }
    __syncthreads();  // barrier2: h planes visible for next A-read
  }
}

extern "C" void kernel_launch(void* const* d_in, const int* in_sizes, int n_in,
                              void* d_out, int out_size, void* d_ws, size_t ws_size,
                              hipStream_t stream) {
  (void)in_sizes; (void)n_in; (void)out_size; (void)ws_size;
  const float* xA    = (const float*)d_in[0];
  const float* xN    = (const float*)d_in[1];
  const int*   cnts  = (const int*)d_in[2];
  const float* Wih_a = (const float*)d_in[3];
  const float* Whh_a = (const float*)d_in[4];
  const float* bih_a = (const float*)d_in[5];
  const float* bhh_a = (const float*)d_in[6];
  const float* Wih_n = (const float*)d_in[7];
  const float* Whh_n = (const float*)d_in[8];
  const float* bih_n = (const float*)d_in[9];
  const float* bhh_n = (const float*)d_in[10];
  const float* Wih_d = (const float*)d_in[11];
  const float* Whh_d = (const float*)d_in[12];
  const float* bih_d = (const float*)d_in[13];
  const float* bhh_d = (const float*)d_in[14];
  const float* Wpos  = (const float*)d_in[15];
  const float* bpos  = (const float*)d_in[16];
  float* out = (float*)d_out;
  float* wsf = (float*)d_ws;

  prep_kernel<<<96, 256, 0, stream>>>(Whh_a, Whh_n, Wih_d, Whh_d, bih_d, bhh_d,
                                      (uint4*)(wsf + OFF_PACKA),
                                      (uint4*)(wsf + OFF_PACKN),
                                      (uint4*)(wsf + OFF_WDP), wsf + OFF_WDB);
  enc_mfma_kernel<<<1088, 256, 0, stream>>>(
      xA, xN,
      (const v8s*)(wsf + OFF_PACKA), (const v8s*)(wsf + OFF_PACKN),
      Wih_a, bih_a, bhh_a, Wih_n, bih_n, bhh_n,
      wsf + OFF_AEMB, wsf + OFF_NENC);
  dec_mfma_kernel<<<256, 512, 0, stream>>>((const v8s*)(wsf + OFF_WDP),
                                           wsf + OFF_WDB, wsf + OFF_AEMB,
                                           wsf + OFF_NENC, cnts,
                                           Wpos, bpos, out);
}

// Round 10
// 343.770 us; speedup vs baseline: 1.1129x; 1.1129x over previous
//
#include <hip/hip_runtime.h>
#include <stdint.h>

// ---------------------------------------------------------------------------
// Social LSTM model, bf16x3 MFMA everywhere.
//   enc:  LSTM(2->64), T=50. 2176 blocks x 4 waves, 16 seqs/block (R8 cfg:
//         R9's 2-group ILP variant REGRESSED -- TLP loss beat ILP gain).
//   pool: fused into dec staging (masked max over nenc, batched loads).
//   dec v4: LSTMCell(128->128), 30 steps. 256 blocks x 16 waves (1024 thr),
//         8 seqs/block. Wave owns gate g=wv&3 x 32 units (2 col-tiles,
//         B = 16 v8s = 64 VGPR, loaded once) -> 4 waves/SIMD. Preds
//         buffered in LDS, single global store at end (no per-step
//         vmcnt(0) drain at the barrier).
// Pointwise: shared-rcp sigmoid/tanh; g-gate weights pre-scaled by 2.
// launch_bounds: enc (256,3) [(256,4) spills -- R6]; dec (1024,4).
// ---------------------------------------------------------------------------

#define T_SEQ 50
#define PRED_STEPS 30
#define NMAX 16

typedef float v2f __attribute__((ext_vector_type(2)));
typedef float v4f __attribute__((ext_vector_type(4)));
typedef short v8s __attribute__((ext_vector_type(8)));

// ws layout (float offsets)
static constexpr size_t OFF_AEMB  = 0;          // 2048*64
static constexpr size_t OFF_NENC  = 131072;     // 32768*64
static constexpr size_t OFF_PACKA = 2490368;    // 64 KB bf16 B-frags (agent)
static constexpr size_t OFF_PACKN = 2507520;    // 64 KB bf16 B-frags (neigh)
static constexpr size_t OFF_WDP   = 2524672;    // 256 KB dec bf16 B-frags
static constexpr size_t OFF_WDB   = 2590208;    // 512 fused dec bias

__device__ __forceinline__ float frcp(float x) { return __builtin_amdgcn_rcpf(x); }
__device__ __forceinline__ unsigned bf16rne(float f) {
  unsigned u = __float_as_uint(f);
  u += 0x7fff + ((u >> 16) & 1);
  return u >> 16;
}
__device__ __forceinline__ float bf16tof(unsigned h) { return __uint_as_float(h << 16); }
__device__ __forceinline__ v4f mfma16(v8s a, v8s b, v4f c) {
  return __builtin_amdgcn_mfma_f32_16x16x32_bf16(a, b, c, 0, 0, 0);
}

// Shared-rcp LSTM cell update. gv PRE-SCALED by 2: eg = exp(-2*g_true).
__device__ __forceinline__ float cell_update(float iv, float fv, float gv,
                                             float ov, float& cref) {
  float ef = __expf(-fv);
  float ei = __expf(-iv);
  float eg = __expf(-gv);
  float t1 = (1.f + ei) * (1.f + eg);
  float rD = frcp((1.f + ef) * t1);
  float sf = t1 * rD;
  float u  = (1.f - eg) * ((1.f + ef) * rD);
  float cn = fmaf(sf, cref, u);
  cref = cn;
  float eo = __expf(-ov);
  float ec = __expf(fminf(-2.f * cn, 41.5f));
  return (1.f - ec) * frcp((1.f + eo) * (1.f + ec));
}

// ---------------------------------------------------------------------------
// Merged prep. Blocks 0..31: encoder packs. Blocks 32..95: decoder pack.
// g-gate (g==2) weights and bias scaled by 2.
// ---------------------------------------------------------------------------
__global__ void prep_kernel(const float* __restrict__ Whh_a, const float* __restrict__ Whh_n,
                            const float* __restrict__ Wih_d, const float* __restrict__ Whh_d,
                            const float* __restrict__ bih_d, const float* __restrict__ bhh_d,
                            uint4* __restrict__ packA, uint4* __restrict__ packN,
                            uint4* __restrict__ packD, float* __restrict__ bd) {
  if (blockIdx.x < 32) {
    const int which = blockIdx.x >> 4;
    const int idx = (blockIdx.x & 15) * 256 + threadIdx.x;  // 0..4095
    const float* Whh = which ? Whh_n : Whh_a;
    uint4* dst = which ? packN : packA;
    const int lane = idx & 63, c = idx >> 6;
    const int p = c & 1, kh = (c >> 1) & 1, g = (c >> 2) & 3, w = (c >> 4) & 3;
    const float gs = (g == 2) ? 2.f : 1.f;
    const int row = g * 64 + 16 * w + (lane & 15);
    const int kb = kh * 32 + (lane >> 4) * 8;
    unsigned us[8];
#pragma unroll
    for (int e = 0; e < 8; ++e) {
      float W = Whh[row * 64 + kb + e] * gs;
      unsigned hi = bf16rne(W);
      us[e] = p ? bf16rne(W - bf16tof(hi)) : hi;
    }
    uint4 o;
    o.x = us[0] | (us[1] << 16);
    o.y = us[2] | (us[3] << 16);
    o.z = us[4] | (us[5] << 16);
    o.w = us[6] | (us[7] << 16);
    dst[c * 64 + lane] = o;
  } else {
    const int idx = (blockIdx.x - 32) * 256 + threadIdx.x;  // 0..16383
    const int lane = idx & 63, c = idx >> 6;
    const int p = c & 1, kh = (c >> 1) & 3, ut = (c >> 3) & 3, uhf = (c >> 5) & 1, g = (c >> 6) & 3;
    const float gs = (g == 2) ? 2.f : 1.f;
    const int j = uhf * 64 + ut * 16 + (lane & 15);
    const int row = g * 128 + j;
    const int kb = kh * 32 + (lane >> 4) * 8;
    unsigned us[8];
#pragma unroll
    for (int e = 0; e < 8; ++e) {
      float W = (Wih_d[row * 128 + kb + e] + Whh_d[row * 128 + kb + e]) * gs;
      unsigned hi = bf16rne(W);
      us[e] = p ? bf16rne(W - bf16tof(hi)) : hi;
    }
    uint4 o;
    o.x = us[0] | (us[1] << 16);
    o.y = us[2] | (us[3] << 16);
    o.z = us[4] | (us[5] << 16);
    o.w = us[6] | (us[7] << 16);
    packD[c * 64 + lane] = o;
    if (blockIdx.x < 34) {
      int i = (blockIdx.x - 32) * 256 + threadIdx.x;  // 0..511
      float s = ((i >> 7) == 2) ? 2.f : 1.f;
      bd[i] = (bih_d[i] + bhh_d[i]) * s;
    }
  }
}

// ---------------------------------------------------------------------------
// Encoder (R8 config). Blocks [0,2048) neighbour, [2048,2176) agent;
// 256 thr = 4 waves, 16 seqs/block. Ping-pong h planes: buf b at halfword
// base b*2304; hi [+0,+1152), lo [+1152,+2304); row stride 72 hw.
// t-loop unrolled x2 -> literal buffer bases. One barrier per t.
// ---------------------------------------------------------------------------
__global__ __launch_bounds__(256, 3) void enc_mfma_kernel(
    const float* __restrict__ xA, const float* __restrict__ xN,
    const v8s* __restrict__ packA, const v8s* __restrict__ packN,
    const float* __restrict__ Wih_a, const float* __restrict__ bih_a, const float* __restrict__ bhh_a,
    const float* __restrict__ Wih_n, const float* __restrict__ bih_n, const float* __restrict__ bhh_n,
    float* __restrict__ outA, float* __restrict__ outN) {
  __shared__ unsigned short hph[4608];  // 2 ping-pong buffers
  __shared__ float xst[1600];
  const int tid = threadIdx.x, lane = tid & 63, wv = tid >> 6;
  const int nb = blockIdx.x;
  const bool isA = nb >= 2048;
  const float* xsrc = isA ? xA : xN;
  const v8s* pk = isA ? packA : packN;
  const float* Wih = isA ? Wih_a : Wih_n;
  const float* bih = isA ? bih_a : bih_n;
  const float* bhh = isA ? bhh_a : bhh_n;
  float* outp = isA ? outA : outN;
  const int s0 = (isA ? nb - 2048 : nb) * 16;

  // register-resident B fragments: [gate][khalf][hi/lo]
  v8s B[4][2][2];
#pragma unroll
  for (int g = 0; g < 4; ++g)
#pragma unroll
    for (int kh = 0; kh < 2; ++kh)
#pragma unroll
      for (int p = 0; p < 2; ++p)
        B[g][kh][p] = pk[((((wv * 4 + g) * 2 + kh) * 2 + p) << 6) + lane];

  const int jc = lane & 15, qc = lane >> 4;  // C roles: unit col, seq quad
  float wi0[4], wi1[4], bs[4];
#pragma unroll
  for (int g = 0; g < 4; ++g) {
    const float gs = (g == 2) ? 2.f : 1.f;
    int n = g * 64 + 16 * wv + jc;
    wi0[g] = Wih[n * 2 + 0] * gs;
    wi1[g] = Wih[n * 2 + 1] * gs;
    bs[g] = (bih[n] + bhh[n]) * gs;
  }

  // stage x (1600 floats) + zero buf0 (1152 dwords)
  {
    const float4* xb = (const float4*)(xsrc + (size_t)s0 * 100);
    for (int i = tid; i < 400; i += 256) ((float4*)xst)[i] = xb[i];
    for (int i = tid; i < 1152; i += 256) ((unsigned*)hph)[i] = 0;
  }
  __syncthreads();

  const int ms = lane & 15, ks = lane >> 4;  // A roles: seq row, k-quad
  float cst[4] = {0.f, 0.f, 0.f, 0.f};
  float h[4];

  auto enc_step = [&](int t, int rb, int wb) {
    v8s Ahi[2], Alo[2];
#pragma unroll
    for (int kh = 0; kh < 2; ++kh) {
      Ahi[kh] = *(const __shared__ v8s*)&hph[rb + ms * 72 + kh * 32 + ks * 8];
      Alo[kh] = *(const __shared__ v8s*)&hph[rb + 1152 + ms * 72 + kh * 32 + ks * 8];
    }

    // acc init: exact fp32 input projection + bias
    v4f a4[4];
#pragma unroll
    for (int r = 0; r < 4; ++r) {
      v2f xv = *(const __shared__ v2f*)&xst[(qc * 4 + r) * 100 + 2 * t];
#pragma unroll
      for (int g = 0; g < 4; ++g)
        a4[g][r] = fmaf(wi1[g], xv.y, fmaf(wi0[g], xv.x, bs[g]));
    }

    // h @ Whh^T via bf16x3 MFMA
#pragma unroll
    for (int g = 0; g < 4; ++g)
#pragma unroll
      for (int kh = 0; kh < 2; ++kh) {
        a4[g] = mfma16(Ahi[kh], B[g][kh][0], a4[g]);
        a4[g] = mfma16(Ahi[kh], B[g][kh][1], a4[g]);
        a4[g] = mfma16(Alo[kh], B[g][kh][0], a4[g]);
      }

    // pointwise + truncation-split b16 stores into the OTHER buffer
#pragma unroll
    for (int r = 0; r < 4; ++r) {
      h[r] = cell_update(a4[0][r], a4[1][r], a4[2][r], a4[3][r], cst[r]);
      unsigned uu = __float_as_uint(h[r]);
      float hif = __uint_as_float(uu & 0xffff0000u);
      float lof = h[r] - hif;
      int ha = wb + (qc * 4 + r) * 72 + 16 * wv + jc;
      hph[ha] = (unsigned short)(uu >> 16);
      hph[1152 + ha] = (unsigned short)(__float_as_uint(lof) >> 16);
    }
    __syncthreads();
  };

  for (int t2 = 0; t2 < T_SEQ; t2 += 2) {
    enc_step(t2 + 0, 0, 2304);      // literal bases -> imm LDS offsets
    enc_step(t2 + 1, 2304, 0);
  }

#pragma unroll
  for (int r = 0; r < 4; ++r)
    outp[(size_t)(s0 + qc * 4 + r) * 64 + 16 * wv + jc] = h[r];
}

// ---------------------------------------------------------------------------
// Decoder MFMA v4. 256 blocks x 1024 thr (16 waves), 8 seqs/block.
// Wave wv: gate g = wv&3, unit-quarter q = wv>>2 -> 2 col-tiles of 16
// units (B = 16 v8s = 64 VGPR). A loaded per-kh (live set small).
// Cell phase: wave pair per seq, 1 cell/thread. Preds buffered in LDS,
// single coalesced global store at the end.
// ---------------------------------------------------------------------------
__global__ __launch_bounds__(1024, 4) void dec_mfma_kernel(
    const v8s* __restrict__ pkd, const float* __restrict__ bd,
    const float* __restrict__ aemb, const float* __restrict__ nenc,
    const int* __restrict__ cnts, const float* __restrict__ Wpos,
    const float* __restrict__ bpos, float* __restrict__ out) {
  __shared__ unsigned short hph[4352];   // hi [0,2176), lo [2176,4352), stride 136
  __shared__ float gbuf[4][8][132];
  __shared__ float ppart[16][2];
  __shared__ float pbuf[480];            // [seq][t][coord]
  const int tid = threadIdx.x, lane = tid & 63, wv = tid >> 6;  // wv 0..15
  const int jc = lane & 15, qc = lane >> 4;
  const int g = wv & 3, q = wv >> 2;
  const int s0 = blockIdx.x * 8;

  // register-resident B fragments: [tile][kh][hi/lo]
  v8s B[2][4][2];
#pragma unroll
  for (int i = 0; i < 2; ++i)
#pragma unroll
    for (int kh = 0; kh < 4; ++kh)
#pragma unroll
      for (int p = 0; p < 2; ++p) {
        int utg = q * 2 + i;
        int c = (g << 6) | ((utg >> 2) << 5) | ((utg & 3) << 3) | (kh << 1) | p;
        B[i][kh][p] = pkd[(c << 6) + lane];
      }
  float bs[2];
#pragma unroll
  for (int i = 0; i < 2; ++i)
    bs[i] = bd[g * 128 + q * 32 + i * 16 + jc];

  // cell-phase constants: seq sq = wv>>1, unit cu = (wv&1)*64 + lane
  const int cu = (wv & 1) * 64 + lane;
  const int sq = wv >> 1;
  const float wp0 = Wpos[cu], wp1 = Wpos[128 + cu];
  const float bp0 = bpos[0], bp1 = bpos[1];

  // stage h0 rows 0..7 (fused hmax, batched loads) + zero rows 8..15
  for (int i = tid; i < 2048; i += 1024) {
    int row = i >> 7, unit = i & 127;
    unsigned hiw = 0, low = 0;
    if (row < 8) {
      float v;
      if (unit < 64) {
        v = aemb[(size_t)(s0 + row) * 64 + unit];
      } else {
        int cnt = cnts[s0 + row];
        float m = -1e30f;
#pragma unroll
        for (int n = 0; n < NMAX; ++n) {
          float val = nenc[((size_t)((s0 + row) * NMAX + n)) * 64 + (unit - 64)];
          m = (n < cnt) ? fmaxf(m, val) : m;
        }
        v = (cnt > 0) ? m : 0.f;
      }
      unsigned u = __float_as_uint(v);
      float hif = __uint_as_float(u & 0xffff0000u);
      float lof = v - hif;
      hiw = u >> 16;
      low = __float_as_uint(lof) >> 16;
    }
    hph[row * 136 + unit] = (unsigned short)hiw;
    hph[2176 + row * 136 + unit] = (unsigned short)low;
  }
  float cst = 0.f;
  __syncthreads();

  for (int t = 0; t < PRED_STEPS; ++t) {
    // MFMA phase: acc over K=128, A loaded per-kh
    v4f acc[2];
#pragma unroll
    for (int i = 0; i < 2; ++i)
      acc[i] = (v4f){bs[i], bs[i], bs[i], bs[i]};
#pragma unroll
    for (int kh = 0; kh < 4; ++kh) {
      v8s Ahi = *(const __shared__ v8s*)&hph[jc * 136 + kh * 32 + qc * 8];
      v8s Alo = *(const __shared__ v8s*)&hph[2176 + jc * 136 + kh * 32 + qc * 8];
#pragma unroll
      for (int i = 0; i < 2; ++i) {
        acc[i] = mfma16(Ahi, B[i][kh][0], acc[i]);
        acc[i] = mfma16(Ahi, B[i][kh][1], acc[i]);
        acc[i] = mfma16(Alo, B[i][kh][0], acc[i]);
      }
    }

    // publish gates (rows 0..7 -> lanes qc<2); banks fully covered
    if (qc < 2) {
#pragma unroll
      for (int i = 0; i < 2; ++i)
#pragma unroll
        for (int r = 0; r < 4; ++r)
          gbuf[g][qc * 4 + r][q * 32 + i * 16 + jc] = acc[i][r];
    }
    __syncthreads();  // barrier1: gates visible, A-reads complete

    // cell phase: 1 cell per thread (seq sq, unit cu)
    float gI = gbuf[0][sq][cu];
    float gF = gbuf[1][sq][cu];
    float gG = gbuf[2][sq][cu];
    float gO = gbuf[3][sq][cu];
    float h = cell_update(gI, gF, gG, gO, cst);

    unsigned uu = __float_as_uint(h);
    float hif = __uint_as_float(uu & 0xffff0000u);
    float lof = h - hif;
    hph[sq * 136 + cu] = (unsigned short)(uu >> 16);
    hph[2176 + sq * 136 + cu] = (unsigned short)(__float_as_uint(lof) >> 16);

    // pred partials: wave covers 64 of the 128 units of seq sq
    float p0 = h * wp0;
    float p1 = h * wp1;
#pragma unroll
    for (int off = 32; off > 0; off >>= 1) {
      p0 += __shfl_xor(p0, off, 64);
      p1 += __shfl_xor(p1, off, 64);
    }
    if (lane == 0) { ppart[wv][0] = p0; ppart[wv][1] = p1; }
    __syncthreads();  // barrier2: h planes + ppart visible

    // combine wave-pair partials into LDS pred buffer (no global store)
    if (tid < 16) {
      int s = tid >> 1, cc = tid & 1;
      pbuf[s * 60 + t * 2 + cc] =
          ppart[2 * s][cc] + ppart[2 * s + 1][cc] + (cc ? bp1 : bp0);
    }
    // safe: ppart next rewritten only after next barrier1; pbuf read at end
  }
  __syncthreads();
  if (tid < 480) out[(size_t)s0 * 60 + tid] = pbuf[tid];
}

extern "C" void kernel_launch(void* const* d_in, const int* in_sizes, int n_in,
                              void* d_out, int out_size, void* d_ws, size_t ws_size,
                              hipStream_t stream) {
  (void)in_sizes; (void)n_in; (void)out_size; (void)ws_size;
  const float* xA    = (const float*)d_in[0];
  const float* xN    = (const float*)d_in[1];
  const int*   cnts  = (const int*)d_in[2];
  const float* Wih_a = (const float*)d_in[3];
  const float* Whh_a = (const float*)d_in[4];
  const float* bih_a = (const float*)d_in[5];
  const float* bhh_a = (const float*)d_in[6];
  const float* Wih_n = (const float*)d_in[7];
  const float* Whh_n = (const float*)d_in[8];
  const float* bih_n = (const float*)d_in[9];
  const float* bhh_n = (const float*)d_in[10];
  const float* Wih_d = (const float*)d_in[11];
  const float* Whh_d = (const float*)d_in[12];
  const float* bih_d = (const float*)d_in[13];
  const float* bhh_d = (const float*)d_in[14];
  const float* Wpos  = (const float*)d_in[15];
  const float* bpos  = (const float*)d_in[16];
  float* out = (float*)d_out;
  float* wsf = (float*)d_ws;

  prep_kernel<<<96, 256, 0, stream>>>(Whh_a, Whh_n, Wih_d, Whh_d, bih_d, bhh_d,
                                      (uint4*)(wsf + OFF_PACKA),
                                      (uint4*)(wsf + OFF_PACKN),
                                      (uint4*)(wsf + OFF_WDP), wsf + OFF_WDB);
  enc_mfma_kernel<<<2176, 256, 0, stream>>>(
      xA, xN,
      (const v8s*)(wsf + OFF_PACKA), (const v8s*)(wsf + OFF_PACKN),
      Wih_a, bih_a, bhh_a, Wih_n, bih_n, bhh_n,
      wsf + OFF_AEMB, wsf + OFF_NENC);
  dec_mfma_kernel<<<256, 1024, 0, stream>>>((const v8s*)(wsf + OFF_WDP),
                                            wsf + OFF_WDB, wsf + OFF_AEMB,
                                            wsf + OFF_NENC, cnts,
                                            Wpos, bpos, out);
}

// Round 11
// 326.416 us; speedup vs baseline: 1.1721x; 1.0532x over previous
//
#include <hip/hip_runtime.h>
#include <stdint.h>

// ---------------------------------------------------------------------------
// Social LSTM model, bf16x2 MFMA (A split hi/lo, B hi-only RNE).
//   enc:  LSTM(2->64), T=50. 2176 blocks x 4 waves, 16 seqs/block.
//         B-frags built INLINE from Whh (no prep dispatch), hi-only ->
//         32 VGPR, launch_bounds(256,4) -> 4 waves/SIMD (R8 was 3: VGPR
//         tier floor(256/VGPR) measured via R6/R8/R9 occupancy).
//   pool: fused into dec staging.
//   dec:  LSTMCell(128->128), 30 steps. 256 blocks x 1024 thr (16 waves).
//         16-wave block forces 4 waves/EU = 64-VGPR cap; v4's x3 B (64
//         VGPR alone) was scratch-spilling -> the constant ~115 us non-enc.
//         v5: B hi-only (32 VGPR), inline build, fits the cap.
// Pointwise: shared-rcp algebra + log2e folded into gate weights so all
// exps are single v_exp (exp2); g-gate additionally x2.
// ---------------------------------------------------------------------------

#define T_SEQ 50
#define PRED_STEPS 30
#define NMAX 16

typedef float v2f __attribute__((ext_vector_type(2)));
typedef float v4f __attribute__((ext_vector_type(4)));
typedef short v8s __attribute__((ext_vector_type(8)));

#define L2E 1.44269504f
#define L2E2 2.88539008f

// ws layout (float offsets)
static constexpr size_t OFF_AEMB = 0;          // 2048*64
static constexpr size_t OFF_NENC = 131072;     // 32768*64

__device__ __forceinline__ float frcp(float x) { return __builtin_amdgcn_rcpf(x); }
#if __has_builtin(__builtin_amdgcn_exp2f)
__device__ __forceinline__ float fexp2(float x) { return __builtin_amdgcn_exp2f(x); }
#else
__device__ __forceinline__ float fexp2(float x) { return exp2f(x); }
#endif
__device__ __forceinline__ unsigned bf16rne(float f) {
  unsigned u = __float_as_uint(f);
  u += 0x7fff + ((u >> 16) & 1);
  return u >> 16;
}
__device__ __forceinline__ v4f mfma16(v8s a, v8s b, v4f c) {
  return __builtin_amdgcn_mfma_f32_16x16x32_bf16(a, b, c, 0, 0, 0);
}

// Shared-rcp LSTM cell. Gates PRE-SCALED: i,f,o by log2e; g by 2*log2e.
__device__ __forceinline__ float cell_update(float iv, float fv, float gv,
                                             float ov, float& cref) {
  float ef = fexp2(-fv);
  float ei = fexp2(-iv);
  float eg = fexp2(-gv);
  float t1 = (1.f + ei) * (1.f + eg);
  float rD = frcp((1.f + ef) * t1);
  float sf = t1 * rD;
  float u  = (1.f - eg) * ((1.f + ef) * rD);
  float cn = fmaf(sf, cref, u);
  cref = cn;
  float eo = fexp2(-ov);
  float ec = fexp2(fminf(-L2E2 * cn, 60.f));
  return (1.f - ec) * frcp((1.f + eo) * (1.f + ec));
}

// Build one hi-only RNE B-fragment from 8 consecutive scaled floats.
__device__ __forceinline__ v8s pack_frag(const float* __restrict__ p, float gs) {
  float4 w0 = *(const float4*)p;
  float4 w1 = *(const float4*)(p + 4);
  uint4 o;
  o.x = bf16rne(w0.x * gs) | (bf16rne(w0.y * gs) << 16);
  o.y = bf16rne(w0.z * gs) | (bf16rne(w0.w * gs) << 16);
  o.z = bf16rne(w1.x * gs) | (bf16rne(w1.y * gs) << 16);
  o.w = bf16rne(w1.z * gs) | (bf16rne(w1.w * gs) << 16);
  return __builtin_bit_cast(v8s, o);
}

// ---------------------------------------------------------------------------
// Encoder. Blocks [0,2048) neighbour, [2048,2176) agent; 256 thr = 4 waves.
// Ping-pong h planes (halfwords): buf b at base b*2304; hi [+0,+1152),
// lo [+1152,+2304); row stride 72. t-loop unrolled x2 -> literal bases.
// ---------------------------------------------------------------------------
__global__ __launch_bounds__(256, 4) void enc_mfma_kernel(
    const float* __restrict__ xA, const float* __restrict__ xN,
    const float* __restrict__ Whh_a, const float* __restrict__ Wih_a,
    const float* __restrict__ bih_a, const float* __restrict__ bhh_a,
    const float* __restrict__ Whh_n, const float* __restrict__ Wih_n,
    const float* __restrict__ bih_n, const float* __restrict__ bhh_n,
    float* __restrict__ outA, float* __restrict__ outN) {
  __shared__ unsigned short hph[4608];
  __shared__ float xst[1600];
  const int tid = threadIdx.x, lane = tid & 63, wv = tid >> 6;
  const int nb = blockIdx.x;
  const bool isA = nb >= 2048;
  const float* xsrc = isA ? xA : xN;
  const float* Whh = isA ? Whh_a : Whh_n;
  const float* Wih = isA ? Wih_a : Wih_n;
  const float* bih = isA ? bih_a : bih_n;
  const float* bhh = isA ? bhh_a : bhh_n;
  float* outp = isA ? outA : outN;
  const int s0 = (isA ? nb - 2048 : nb) * 16;

  // inline B-frag build, hi-only: lane role n=lane&15, k-quad=lane>>4
  const int fr = lane & 15, fq = lane >> 4;
  v8s B[4][2];
#pragma unroll
  for (int g = 0; g < 4; ++g) {
    const float gs = (g == 2) ? L2E2 : L2E;
    const int row = g * 64 + 16 * wv + fr;
#pragma unroll
    for (int kh = 0; kh < 2; ++kh)
      B[g][kh] = pack_frag(Whh + row * 64 + kh * 32 + fq * 8, gs);
  }

  const int jc = lane & 15, qc = lane >> 4;  // C roles: unit col, seq quad
  float wi0[4], wi1[4], bs[4];
#pragma unroll
  for (int g = 0; g < 4; ++g) {
    const float gs = (g == 2) ? L2E2 : L2E;
    int n = g * 64 + 16 * wv + jc;
    wi0[g] = Wih[n * 2 + 0] * gs;
    wi1[g] = Wih[n * 2 + 1] * gs;
    bs[g] = (bih[n] + bhh[n]) * gs;
  }

  // stage x (1600 floats) + zero buf0 (1152 dwords)
  {
    const float4* xb = (const float4*)(xsrc + (size_t)s0 * 100);
    for (int i = tid; i < 400; i += 256) ((float4*)xst)[i] = xb[i];
    for (int i = tid; i < 1152; i += 256) ((unsigned*)hph)[i] = 0;
  }
  __syncthreads();

  const int ms = lane & 15, ks = lane >> 4;  // A roles: seq row, k-quad
  float cst[4] = {0.f, 0.f, 0.f, 0.f};
  float h[4];

  auto enc_step = [&](int t, int rb, int wb) {
    // acc init: exact fp32 input projection + bias (scaled)
    v4f a4[4];
#pragma unroll
    for (int r = 0; r < 4; ++r) {
      v2f xv = *(const __shared__ v2f*)&xst[(qc * 4 + r) * 100 + 2 * t];
#pragma unroll
      for (int g = 0; g < 4; ++g)
        a4[g][r] = fmaf(wi1[g], xv.y, fmaf(wi0[g], xv.x, bs[g]));
    }

    // h @ Whh^T, bf16x2: (Ahi + Alo) x Bhi ; A loaded per-kh (low live set)
#pragma unroll
    for (int kh = 0; kh < 2; ++kh) {
      v8s Ahi = *(const __shared__ v8s*)&hph[rb + ms * 72 + kh * 32 + ks * 8];
      v8s Alo = *(const __shared__ v8s*)&hph[rb + 1152 + ms * 72 + kh * 32 + ks * 8];
#pragma unroll
      for (int g = 0; g < 4; ++g) {
        a4[g] = mfma16(Ahi, B[g][kh], a4[g]);
        a4[g] = mfma16(Alo, B[g][kh], a4[g]);
      }
    }

    // pointwise + truncation-split b16 stores into the OTHER buffer
#pragma unroll
    for (int r = 0; r < 4; ++r) {
      h[r] = cell_update(a4[0][r], a4[1][r], a4[2][r], a4[3][r], cst[r]);
      unsigned uu = __float_as_uint(h[r]);
      float hif = __uint_as_float(uu & 0xffff0000u);
      float lof = h[r] - hif;
      int ha = wb + (qc * 4 + r) * 72 + 16 * wv + jc;
      hph[ha] = (unsigned short)(uu >> 16);
      hph[1152 + ha] = (unsigned short)(__float_as_uint(lof) >> 16);
    }
    __syncthreads();
  };

  for (int t2 = 0; t2 < T_SEQ; t2 += 2) {
    enc_step(t2 + 0, 0, 2304);
    enc_step(t2 + 1, 2304, 0);
  }

#pragma unroll
  for (int r = 0; r < 4; ++r)
    outp[(size_t)(s0 + qc * 4 + r) * 64 + 16 * wv + jc] = h[r];
}

// ---------------------------------------------------------------------------
// Decoder v5. 256 blocks x 1024 thr (16 waves), 8 seqs/block.
// Wave wv: gate g = wv&3, unit-quarter q = wv>>2 -> 2 col-tiles of 16
// units, B hi-only (8 v8s = 32 VGPR) built inline -> fits the 64-VGPR
// cap that a 16-wave block forces (4 waves/EU). Preds in LDS, one store.
// ---------------------------------------------------------------------------
__global__ __launch_bounds__(1024, 4) void dec_mfma_kernel(
    const float* __restrict__ Wih_d, const float* __restrict__ Whh_d,
    const float* __restrict__ bih_d, const float* __restrict__ bhh_d,
    const float* __restrict__ aemb, const float* __restrict__ nenc,
    const int* __restrict__ cnts, const float* __restrict__ Wpos,
    const float* __restrict__ bpos, float* __restrict__ out) {
  __shared__ unsigned short hph[4352];   // hi [0,2176), lo [2176,4352), stride 136
  __shared__ float gbuf[4][8][132];
  __shared__ float ppart[16][2];
  __shared__ float pbuf[480];
  const int tid = threadIdx.x, lane = tid & 63, wv = tid >> 6;  // wv 0..15
  const int jc = lane & 15, qc = lane >> 4;
  const int g = wv & 3, q = wv >> 2;
  const int s0 = blockIdx.x * 8;

  // inline B-frag build (hi-only): W = (Wih_d + Whh_d) * gs
  const float gs = (g == 2) ? L2E2 : L2E;
  v8s B[2][4];
  float bs[2];
#pragma unroll
  for (int i = 0; i < 2; ++i) {
    const int ju = q * 32 + i * 16 + jc;     // unit for tile i (frag role = jc)
    const int row = g * 128 + ju;
#pragma unroll
    for (int kh = 0; kh < 4; ++kh) {
      const int off = row * 128 + kh * 32 + qc * 8;
      float4 a0 = *(const float4*)(Wih_d + off);
      float4 a1 = *(const float4*)(Wih_d + off + 4);
      float4 b0 = *(const float4*)(Whh_d + off);
      float4 b1 = *(const float4*)(Whh_d + off + 4);
      uint4 o;
      o.x = bf16rne((a0.x + b0.x) * gs) | (bf16rne((a0.y + b0.y) * gs) << 16);
      o.y = bf16rne((a0.z + b0.z) * gs) | (bf16rne((a0.w + b0.w) * gs) << 16);
      o.z = bf16rne((a1.x + b1.x) * gs) | (bf16rne((a1.y + b1.y) * gs) << 16);
      o.w = bf16rne((a1.z + b1.z) * gs) | (bf16rne((a1.w + b1.w) * gs) << 16);
      B[i][kh] = __builtin_bit_cast(v8s, o);
    }
    bs[i] = (bih_d[row] + bhh_d[row]) * gs;
  }

  // cell-phase constants: seq sq = wv>>1, unit cu = (wv&1)*64 + lane
  const int cu = (wv & 1) * 64 + lane;
  const int sq = wv >> 1;
  const float wp0 = Wpos[cu], wp1 = Wpos[128 + cu];
  const float bp0 = bpos[0], bp1 = bpos[1];

  // stage h0 rows 0..7 (fused hmax, batched loads) + zero rows 8..15
  for (int i = tid; i < 2048; i += 1024) {
    int row = i >> 7, unit = i & 127;
    unsigned hiw = 0, low = 0;
    if (row < 8) {
      float v;
      if (unit < 64) {
        v = aemb[(size_t)(s0 + row) * 64 + unit];
      } else {
        int cnt = cnts[s0 + row];
        float m = -1e30f;
#pragma unroll
        for (int n = 0; n < NMAX; ++n) {
          float val = nenc[((size_t)((s0 + row) * NMAX + n)) * 64 + (unit - 64)];
          m = (n < cnt) ? fmaxf(m, val) : m;
        }
        v = (cnt > 0) ? m : 0.f;
      }
      unsigned u = __float_as_uint(v);
      float hif = __uint_as_float(u & 0xffff0000u);
      float lof = v - hif;
      hiw = u >> 16;
      low = __float_as_uint(lof) >> 16;
    }
    hph[row * 136 + unit] = (unsigned short)hiw;
    hph[2176 + row * 136 + unit] = (unsigned short)low;
  }
  float cst = 0.f;
  __syncthreads();

  for (int t = 0; t < PRED_STEPS; ++t) {
    v4f acc[2];
#pragma unroll
    for (int i = 0; i < 2; ++i)
      acc[i] = (v4f){bs[i], bs[i], bs[i], bs[i]};
#pragma unroll
    for (int kh = 0; kh < 4; ++kh) {
      v8s Ahi = *(const __shared__ v8s*)&hph[jc * 136 + kh * 32 + qc * 8];
      v8s Alo = *(const __shared__ v8s*)&hph[2176 + jc * 136 + kh * 32 + qc * 8];
#pragma unroll
      for (int i = 0; i < 2; ++i) {
        acc[i] = mfma16(Ahi, B[i][kh], acc[i]);
        acc[i] = mfma16(Alo, B[i][kh], acc[i]);
      }
    }

    // publish gates (rows 0..7 -> lanes qc<2)
    if (qc < 2) {
#pragma unroll
      for (int i = 0; i < 2; ++i)
#pragma unroll
        for (int r = 0; r < 4; ++r)
          gbuf[g][qc * 4 + r][q * 32 + i * 16 + jc] = acc[i][r];
    }
    __syncthreads();  // barrier1: gates visible, A-reads complete

    // cell phase: 1 cell per thread (seq sq, unit cu)
    float gI = gbuf[0][sq][cu];
    float gF = gbuf[1][sq][cu];
    float gG = gbuf[2][sq][cu];
    float gO = gbuf[3][sq][cu];
    float h = cell_update(gI, gF, gG, gO, cst);

    unsigned uu = __float_as_uint(h);
    float hif = __uint_as_float(uu & 0xffff0000u);
    float lof = h - hif;
    hph[sq * 136 + cu] = (unsigned short)(uu >> 16);
    hph[2176 + sq * 136 + cu] = (unsigned short)(__float_as_uint(lof) >> 16);

    // pred partials: wave covers 64 of 128 units of seq sq
    float p0 = h * wp0;
    float p1 = h * wp1;
#pragma unroll
    for (int off = 32; off > 0; off >>= 1) {
      p0 += __shfl_xor(p0, off, 64);
      p1 += __shfl_xor(p1, off, 64);
    }
    if (lane == 0) { ppart[wv][0] = p0; ppart[wv][1] = p1; }
    __syncthreads();  // barrier2: h planes + ppart visible

    if (tid < 16) {
      int s = tid >> 1, cc = tid & 1;
      pbuf[s * 60 + t * 2 + cc] =
          ppart[2 * s][cc] + ppart[2 * s + 1][cc] + (cc ? bp1 : bp0);
    }
  }
  __syncthreads();
  if (tid < 480) out[(size_t)s0 * 60 + tid] = pbuf[tid];
}

extern "C" void kernel_launch(void* const* d_in, const int* in_sizes, int n_in,
                              void* d_out, int out_size, void* d_ws, size_t ws_size,
                              hipStream_t stream) {
  (void)in_sizes; (void)n_in; (void)out_size; (void)ws_size;
  const float* xA    = (const float*)d_in[0];
  const float* xN    = (const float*)d_in[1];
  const int*   cnts  = (const int*)d_in[2];
  const float* Wih_a = (const float*)d_in[3];
  const float* Whh_a = (const float*)d_in[4];
  const float* bih_a = (const float*)d_in[5];
  const float* bhh_a = (const float*)d_in[6];
  const float* Wih_n = (const float*)d_in[7];
  const float* Whh_n = (const float*)d_in[8];
  const float* bih_n = (const float*)d_in[9];
  const float* bhh_n = (const float*)d_in[10];
  const float* Wih_d = (const float*)d_in[11];
  const float* Whh_d = (const float*)d_in[12];
  const float* bih_d = (const float*)d_in[13];
  const float* bhh_d = (const float*)d_in[14];
  const float* Wpos  = (const float*)d_in[15];
  const float* bpos  = (const float*)d_in[16];
  float* out = (float*)d_out;
  float* wsf = (float*)d_ws;

  enc_mfma_kernel<<<2176, 256, 0, stream>>>(
      xA, xN,
      Whh_a, Wih_a, bih_a, bhh_a,
      Whh_n, Wih_n, bih_n, bhh_n,
      wsf + OFF_AEMB, wsf + OFF_NENC);
  dec_mfma_kernel<<<256, 1024, 0, stream>>>(
      Wih_d, Whh_d, bih_d, bhh_d,
      wsf + OFF_AEMB, wsf + OFF_NENC, cnts,
      Wpos, bpos, out);
}

// Round 12
// 301.595 us; speedup vs baseline: 1.2686x; 1.0823x over previous
//
#include <hip/hip_runtime.h>
#include <stdint.h>

// ---------------------------------------------------------------------------
// Social LSTM model, bf16x2 MFMA (A split hi/lo, B hi-only RNE).
//   prep: ONE small dispatch packs B-frags (hi-only, log2e/2*log2e folded)
//         for enc-A/enc-N/dec + fused dec bias into ws. Coalesced reads in
//         the hot kernels (R11's inline scattered build cost ~20 us in dec
//         and ~10 us in enc via 4x cache-line amplification).
//   enc:  LSTM(2->64), T=50. 2176 blocks x 4 waves, 16 seqs/block.
//         VGPR 60 -> launch_bounds(256,4) = 4 waves/SIMD (R11 win).
//   pool: fused into dec staging.
//   dec:  LSTMCell(128->128), 30 steps. 256 blocks x 1024 thr (16 waves),
//         B hi-only 8 v8s = 32 VGPR -> fits the 64-VGPR cap a 16-wave
//         block forces. Preds buffered in LDS, one global store.
// Pointwise: shared-rcp algebra, exp2-only transcendentals.
// ---------------------------------------------------------------------------

#define T_SEQ 50
#define PRED_STEPS 30
#define NMAX 16

typedef float v2f __attribute__((ext_vector_type(2)));
typedef float v4f __attribute__((ext_vector_type(4)));
typedef short v8s __attribute__((ext_vector_type(8)));

#define L2E 1.44269504f
#define L2E2 2.88539008f

// ws layout (float offsets)
static constexpr size_t OFF_AEMB  = 0;          // 2048*64
static constexpr size_t OFF_NENC  = 131072;     // 32768*64
static constexpr size_t OFF_PACKA = 2490368;    // 8192 floats (32 KB pack)
static constexpr size_t OFF_PACKN = 2498560;    // 8192 floats
static constexpr size_t OFF_WDP   = 2506752;    // 32768 floats (128 KB pack)
static constexpr size_t OFF_WDB   = 2539520;    // 512 floats fused dec bias

__device__ __forceinline__ float frcp(float x) { return __builtin_amdgcn_rcpf(x); }
#if __has_builtin(__builtin_amdgcn_exp2f)
__device__ __forceinline__ float fexp2(float x) { return __builtin_amdgcn_exp2f(x); }
#else
__device__ __forceinline__ float fexp2(float x) { return exp2f(x); }
#endif
__device__ __forceinline__ unsigned bf16rne(float f) {
  unsigned u = __float_as_uint(f);
  u += 0x7fff + ((u >> 16) & 1);
  return u >> 16;
}
__device__ __forceinline__ v4f mfma16(v8s a, v8s b, v4f c) {
  return __builtin_amdgcn_mfma_f32_16x16x32_bf16(a, b, c, 0, 0, 0);
}

// Shared-rcp LSTM cell. Gates PRE-SCALED: i,f,o by log2e; g by 2*log2e.
__device__ __forceinline__ float cell_update(float iv, float fv, float gv,
                                             float ov, float& cref) {
  float ef = fexp2(-fv);
  float ei = fexp2(-iv);
  float eg = fexp2(-gv);
  float t1 = (1.f + ei) * (1.f + eg);
  float rD = frcp((1.f + ef) * t1);
  float sf = t1 * rD;
  float u  = (1.f - eg) * ((1.f + ef) * rD);
  float cn = fmaf(sf, cref, u);
  cref = cn;
  float eo = fexp2(-ov);
  float ec = fexp2(fminf(-L2E2 * cn, 60.f));
  return (1.f - ec) * frcp((1.f + eo) * (1.f + ec));
}

// pack 8 consecutive scaled floats -> hi-only RNE bf16x8 (one uint4)
__device__ __forceinline__ uint4 pack8(const float* __restrict__ p, float gs) {
  float4 w0 = *(const float4*)p;
  float4 w1 = *(const float4*)(p + 4);
  uint4 o;
  o.x = bf16rne(w0.x * gs) | (bf16rne(w0.y * gs) << 16);
  o.y = bf16rne(w0.z * gs) | (bf16rne(w0.w * gs) << 16);
  o.z = bf16rne(w1.x * gs) | (bf16rne(w1.y * gs) << 16);
  o.w = bf16rne(w1.z * gs) | (bf16rne(w1.w * gs) << 16);
  return o;
}
__device__ __forceinline__ uint4 pack8sum(const float* __restrict__ pa,
                                          const float* __restrict__ pb, float gs) {
  float4 a0 = *(const float4*)pa, a1 = *(const float4*)(pa + 4);
  float4 b0 = *(const float4*)pb, b1 = *(const float4*)(pb + 4);
  uint4 o;
  o.x = bf16rne((a0.x + b0.x) * gs) | (bf16rne((a0.y + b0.y) * gs) << 16);
  o.y = bf16rne((a0.z + b0.z) * gs) | (bf16rne((a0.w + b0.w) * gs) << 16);
  o.z = bf16rne((a1.x + b1.x) * gs) | (bf16rne((a1.y + b1.y) * gs) << 16);
  o.w = bf16rne((a1.z + b1.z) * gs) | (bf16rne((a1.w + b1.w) * gs) << 16);
  return o;
}

// ---------------------------------------------------------------------------
// Merged prep, 48 blocks x 256.
//  b in [0,16): enc packs (b<8: agent, else neighbour). chunk c = w*8+g*2+kh,
//    lane l: row = g*64+16w+(l&15), k = kh*32+(l>>4)*8.
//  b in [16,48): dec pack. chunk c = wv*8+i*4+kh, lane l:
//    ju = q*32+i*16+(l&15) (q=wv>>2, g=wv&3), row = g*128+ju,
//    k = kh*32+(l>>4)*8, W = (Wih_d+Whh_d)*gs.  First 2 blocks: bias.
// ---------------------------------------------------------------------------
__global__ void prep_kernel(const float* __restrict__ Whh_a, const float* __restrict__ Whh_n,
                            const float* __restrict__ Wih_d, const float* __restrict__ Whh_d,
                            const float* __restrict__ bih_d, const float* __restrict__ bhh_d,
                            uint4* __restrict__ packA, uint4* __restrict__ packN,
                            uint4* __restrict__ packD, float* __restrict__ bd) {
  const int b = blockIdx.x;
  if (b < 16) {
    const int which = b >> 3;
    const float* Whh = which ? Whh_n : Whh_a;
    uint4* dst = which ? packN : packA;
    const int idx = (b & 7) * 256 + threadIdx.x;   // 0..2047
    const int lane = idx & 63, c = idx >> 6;       // c 0..31
    const int kh = c & 1, g = (c >> 1) & 3, w = c >> 3;
    const float gs = (g == 2) ? L2E2 : L2E;
    const int row = g * 64 + 16 * w + (lane & 15);
    const int kb = kh * 32 + (lane >> 4) * 8;
    dst[c * 64 + lane] = pack8(Whh + row * 64 + kb, gs);
  } else {
    const int idx = (b - 16) * 256 + threadIdx.x;  // 0..8191
    const int lane = idx & 63, c = idx >> 6;       // c 0..127
    const int kh = c & 3, i = (c >> 2) & 1, wv = c >> 3;
    const int g = wv & 3, q = wv >> 2;
    const float gs = (g == 2) ? L2E2 : L2E;
    const int ju = q * 32 + i * 16 + (lane & 15);
    const int row = g * 128 + ju;
    const int kb = kh * 32 + (lane >> 4) * 8;
    packD[c * 64 + lane] = pack8sum(Wih_d + row * 128 + kb, Whh_d + row * 128 + kb, gs);
    if (b < 18) {
      int iB = (b - 16) * 256 + threadIdx.x;       // 0..511
      float s = ((iB >> 7) == 2) ? L2E2 : L2E;
      bd[iB] = (bih_d[iB] + bhh_d[iB]) * s;
    }
  }
}

// ---------------------------------------------------------------------------
// Encoder. Blocks [0,2048) neighbour, [2048,2176) agent; 256 thr = 4 waves.
// Ping-pong h planes (halfwords): buf b at base b*2304; hi [+0,+1152),
// lo [+1152,+2304); row stride 72. t-loop unrolled x2 -> literal bases.
// ---------------------------------------------------------------------------
__global__ __launch_bounds__(256, 4) void enc_mfma_kernel(
    const float* __restrict__ xA, const float* __restrict__ xN,
    const v8s* __restrict__ packA, const v8s* __restrict__ packN,
    const float* __restrict__ Wih_a, const float* __restrict__ bih_a, const float* __restrict__ bhh_a,
    const float* __restrict__ Wih_n, const float* __restrict__ bih_n, const float* __restrict__ bhh_n,
    float* __restrict__ outA, float* __restrict__ outN) {
  __shared__ unsigned short hph[4608];
  __shared__ float xst[1600];
  const int tid = threadIdx.x, lane = tid & 63, wv = tid >> 6;
  const int nb = blockIdx.x;
  const bool isA = nb >= 2048;
  const float* xsrc = isA ? xA : xN;
  const v8s* pk = isA ? packA : packN;
  const float* Wih = isA ? Wih_a : Wih_n;
  const float* bih = isA ? bih_a : bih_n;
  const float* bhh = isA ? bhh_a : bhh_n;
  float* outp = isA ? outA : outN;
  const int s0 = (isA ? nb - 2048 : nb) * 16;

  // coalesced B-frag load (hi-only): chunk = wv*8+g*2+kh
  v8s B[4][2];
#pragma unroll
  for (int g = 0; g < 4; ++g)
#pragma unroll
    for (int kh = 0; kh < 2; ++kh)
      B[g][kh] = pk[(wv * 8 + g * 2 + kh) * 64 + lane];

  const int jc = lane & 15, qc = lane >> 4;  // C roles: unit col, seq quad
  float wi0[4], wi1[4], bs[4];
#pragma unroll
  for (int g = 0; g < 4; ++g) {
    const float gs = (g == 2) ? L2E2 : L2E;
    int n = g * 64 + 16 * wv + jc;
    wi0[g] = Wih[n * 2 + 0] * gs;
    wi1[g] = Wih[n * 2 + 1] * gs;
    bs[g] = (bih[n] + bhh[n]) * gs;
  }

  // stage x (1600 floats) + zero buf0 (1152 dwords)
  {
    const float4* xb = (const float4*)(xsrc + (size_t)s0 * 100);
    for (int i = tid; i < 400; i += 256) ((float4*)xst)[i] = xb[i];
    for (int i = tid; i < 1152; i += 256) ((unsigned*)hph)[i] = 0;
  }
  __syncthreads();

  const int ms = lane & 15, ks = lane >> 4;  // A roles: seq row, k-quad
  float cst[4] = {0.f, 0.f, 0.f, 0.f};
  float h[4];

  auto enc_step = [&](int t, int rb, int wb) {
    // acc init: exact fp32 input projection + bias (scaled)
    v4f a4[4];
#pragma unroll
    for (int r = 0; r < 4; ++r) {
      v2f xv = *(const __shared__ v2f*)&xst[(qc * 4 + r) * 100 + 2 * t];
#pragma unroll
      for (int g = 0; g < 4; ++g)
        a4[g][r] = fmaf(wi1[g], xv.y, fmaf(wi0[g], xv.x, bs[g]));
    }

    // h @ Whh^T, bf16x2: (Ahi + Alo) x Bhi ; A loaded per-kh
#pragma unroll
    for (int kh = 0; kh < 2; ++kh) {
      v8s Ahi = *(const __shared__ v8s*)&hph[rb + ms * 72 + kh * 32 + ks * 8];
      v8s Alo = *(const __shared__ v8s*)&hph[rb + 1152 + ms * 72 + kh * 32 + ks * 8];
#pragma unroll
      for (int g = 0; g < 4; ++g) {
        a4[g] = mfma16(Ahi, B[g][kh], a4[g]);
        a4[g] = mfma16(Alo, B[g][kh], a4[g]);
      }
    }

    // pointwise + truncation-split b16 stores into the OTHER buffer
#pragma unroll
    for (int r = 0; r < 4; ++r) {
      h[r] = cell_update(a4[0][r], a4[1][r], a4[2][r], a4[3][r], cst[r]);
      unsigned uu = __float_as_uint(h[r]);
      float hif = __uint_as_float(uu & 0xffff0000u);
      float lof = h[r] - hif;
      int ha = wb + (qc * 4 + r) * 72 + 16 * wv + jc;
      hph[ha] = (unsigned short)(uu >> 16);
      hph[1152 + ha] = (unsigned short)(__float_as_uint(lof) >> 16);
    }
    __syncthreads();
  };

  for (int t2 = 0; t2 < T_SEQ; t2 += 2) {
    enc_step(t2 + 0, 0, 2304);
    enc_step(t2 + 1, 2304, 0);
  }

#pragma unroll
  for (int r = 0; r < 4; ++r)
    outp[(size_t)(s0 + qc * 4 + r) * 64 + 16 * wv + jc] = h[r];
}

// ---------------------------------------------------------------------------
// Decoder v6. 256 blocks x 1024 thr (16 waves), 8 seqs/block.
// Wave wv: gate g = wv&3, unit-quarter q = wv>>2 -> 2 col-tiles of 16
// units, B hi-only (8 v8s = 32 VGPR) via coalesced pack read.
// Preds buffered in LDS, single store at the end.
// ---------------------------------------------------------------------------
__global__ __launch_bounds__(1024, 4) void dec_mfma_kernel(
    const v8s* __restrict__ pkd, const float* __restrict__ bd,
    const float* __restrict__ aemb, const float* __restrict__ nenc,
    const int* __restrict__ cnts, const float* __restrict__ Wpos,
    const float* __restrict__ bpos, float* __restrict__ out) {
  __shared__ unsigned short hph[4352];   // hi [0,2176), lo [2176,4352), stride 136
  __shared__ float gbuf[4][8][132];
  __shared__ float ppart[16][2];
  __shared__ float pbuf[480];
  const int tid = threadIdx.x, lane = tid & 63, wv = tid >> 6;  // wv 0..15
  const int jc = lane & 15, qc = lane >> 4;
  const int g = wv & 3, q = wv >> 2;
  const int s0 = blockIdx.x * 8;

  // coalesced B-frag load: chunk = wv*8+i*4+kh
  v8s B[2][4];
  float bs[2];
#pragma unroll
  for (int i = 0; i < 2; ++i) {
#pragma unroll
    for (int kh = 0; kh < 4; ++kh)
      B[i][kh] = pkd[(wv * 8 + i * 4 + kh) * 64 + lane];
    bs[i] = bd[g * 128 + q * 32 + i * 16 + jc];
  }

  // cell-phase constants: seq sq = wv>>1, unit cu = (wv&1)*64 + lane
  const int cu = (wv & 1) * 64 + lane;
  const int sq = wv >> 1;
  const float wp0 = Wpos[cu], wp1 = Wpos[128 + cu];
  const float bp0 = bpos[0], bp1 = bpos[1];

  // stage h0 rows 0..7 (fused hmax, batched loads) + zero rows 8..15
  for (int i = tid; i < 2048; i += 1024) {
    int row = i >> 7, unit = i & 127;
    unsigned hiw = 0, low = 0;
    if (row < 8) {
      float v;
      if (unit < 64) {
        v = aemb[(size_t)(s0 + row) * 64 + unit];
      } else {
        int cnt = cnts[s0 + row];
        float m = -1e30f;
#pragma unroll
        for (int n = 0; n < NMAX; ++n) {
          float val = nenc[((size_t)((s0 + row) * NMAX + n)) * 64 + (unit - 64)];
          m = (n < cnt) ? fmaxf(m, val) : m;
        }
        v = (cnt > 0) ? m : 0.f;
      }
      unsigned u = __float_as_uint(v);
      float hif = __uint_as_float(u & 0xffff0000u);
      float lof = v - hif;
      hiw = u >> 16;
      low = __float_as_uint(lof) >> 16;
    }
    hph[row * 136 + unit] = (unsigned short)hiw;
    hph[2176 + row * 136 + unit] = (unsigned short)low;
  }
  float cst = 0.f;
  __syncthreads();

  for (int t = 0; t < PRED_STEPS; ++t) {
    v4f acc[2];
#pragma unroll
    for (int i = 0; i < 2; ++i)
      acc[i] = (v4f){bs[i], bs[i], bs[i], bs[i]};
#pragma unroll
    for (int kh = 0; kh < 4; ++kh) {
      v8s Ahi = *(const __shared__ v8s*)&hph[jc * 136 + kh * 32 + qc * 8];
      v8s Alo = *(const __shared__ v8s*)&hph[2176 + jc * 136 + kh * 32 + qc * 8];
#pragma unroll
      for (int i = 0; i < 2; ++i) {
        acc[i] = mfma16(Ahi, B[i][kh], acc[i]);
        acc[i] = mfma16(Alo, B[i][kh], acc[i]);
      }
    }

    // publish gates (rows 0..7 -> lanes qc<2)
    if (qc < 2) {
#pragma unroll
      for (int i = 0; i < 2; ++i)
#pragma unroll
        for (int r = 0; r < 4; ++r)
          gbuf[g][qc * 4 + r][q * 32 + i * 16 + jc] = acc[i][r];
    }
    __syncthreads();  // barrier1: gates visible, A-reads complete

    // cell phase: 1 cell per thread (seq sq, unit cu)
    float gI = gbuf[0][sq][cu];
    float gF = gbuf[1][sq][cu];
    float gG = gbuf[2][sq][cu];
    float gO = gbuf[3][sq][cu];
    float h = cell_update(gI, gF, gG, gO, cst);

    unsigned uu = __float_as_uint(h);
    float hif = __uint_as_float(uu & 0xffff0000u);
    float lof = h - hif;
    hph[sq * 136 + cu] = (unsigned short)(uu >> 16);
    hph[2176 + sq * 136 + cu] = (unsigned short)(__float_as_uint(lof) >> 16);

    // pred partials: wave covers 64 of 128 units of seq sq
    float p0 = h * wp0;
    float p1 = h * wp1;
#pragma unroll
    for (int off = 32; off > 0; off >>= 1) {
      p0 += __shfl_xor(p0, off, 64);
      p1 += __shfl_xor(p1, off, 64);
    }
    if (lane == 0) { ppart[wv][0] = p0; ppart[wv][1] = p1; }
    __syncthreads();  // barrier2: h planes + ppart visible

    if (tid < 16) {
      int s = tid >> 1, cc = tid & 1;
      pbuf[s * 60 + t * 2 + cc] =
          ppart[2 * s][cc] + ppart[2 * s + 1][cc] + (cc ? bp1 : bp0);
    }
  }
  __syncthreads();
  if (tid < 480) out[(size_t)s0 * 60 + tid] = pbuf[tid];
}

extern "C" void kernel_launch(void* const* d_in, const int* in_sizes, int n_in,
                              void* d_out, int out_size, void* d_ws, size_t ws_size,
                              hipStream_t stream) {
  (void)in_sizes; (void)n_in; (void)out_size; (void)ws_size;
  const float* xA    = (const float*)d_in[0];
  const float* xN    = (const float*)d_in[1];
  const int*   cnts  = (const int*)d_in[2];
  const float* Wih_a = (const float*)d_in[3];
  const float* Whh_a = (const float*)d_in[4];
  const float* bih_a = (const float*)d_in[5];
  const float* bhh_a = (const float*)d_in[6];
  const float* Wih_n = (const float*)d_in[7];
  const float* Whh_n = (const float*)d_in[8];
  const float* bih_n = (const float*)d_in[9];
  const float* bhh_n = (const float*)d_in[10];
  const float* Wih_d = (const float*)d_in[11];
  const float* Whh_d = (const float*)d_in[12];
  const float* bih_d = (const float*)d_in[13];
  const float* bhh_d = (const float*)d_in[14];
  const float* Wpos  = (const float*)d_in[15];
  const float* bpos  = (const float*)d_in[16];
  float* out = (float*)d_out;
  float* wsf = (float*)d_ws;

  prep_kernel<<<48, 256, 0, stream>>>(Whh_a, Whh_n, Wih_d, Whh_d, bih_d, bhh_d,
                                      (uint4*)(wsf + OFF_PACKA),
                                      (uint4*)(wsf + OFF_PACKN),
                                      (uint4*)(wsf + OFF_WDP), wsf + OFF_WDB);
  enc_mfma_kernel<<<2176, 256, 0, stream>>>(
      xA, xN,
      (const v8s*)(wsf + OFF_PACKA), (const v8s*)(wsf + OFF_PACKN),
      Wih_a, bih_a, bhh_a, Wih_n, bih_n, bhh_n,
      wsf + OFF_AEMB, wsf + OFF_NENC);
  dec_mfma_kernel<<<256, 1024, 0, stream>>>(
      (const v8s*)(wsf + OFF_WDP), wsf + OFF_WDB,
      wsf + OFF_AEMB, wsf + OFF_NENC, cnts,
      Wpos, bpos, out);
}

// Round 13
// 267.418 us; speedup vs baseline: 1.4307x; 1.1278x over previous
//
#include <hip/hip_runtime.h>
#include <stdint.h>

// ---------------------------------------------------------------------------
// Social LSTM model, bf16 MFMA: A hi-only (RNE), B hi-only (RNE).
//   prep: one dispatch packs B-frags (log2e/2*log2e folded) + dec bias.
//   enc:  LSTM(2->64), T=50. 2176 blocks x 4 waves, 16 seqs/block.
//         8 MFMA/wave-step (was 16 with A hi/lo); h planes hi-only ->
//         half the LDS, no split math. VGPR-60 / launch_bounds(256,4).
//   pool: fused into dec staging.
//   dec:  LSTMCell(128->128), 30 steps. 256 blocks x 1024 thr (16 waves),
//         8 MFMA/wave-step. Preds in LDS, one store.
// Accuracy ledger: absmax sat at 2^-10 (threshold 5.078e-3) from pure-fp32
// R1 through B-hi-only R12 -> error is reassociation-dominated; A-hi adds
// 2^-9-rel h quantization, same order as existing B quantization.
// Pointwise: shared-rcp algebra, exp2-only transcendentals.
// ---------------------------------------------------------------------------

#define T_SEQ 50
#define PRED_STEPS 30
#define NMAX 16

typedef float v2f __attribute__((ext_vector_type(2)));
typedef float v4f __attribute__((ext_vector_type(4)));
typedef short v8s __attribute__((ext_vector_type(8)));

#define L2E 1.44269504f
#define L2E2 2.88539008f

// ws layout (float offsets)
static constexpr size_t OFF_AEMB  = 0;          // 2048*64
static constexpr size_t OFF_NENC  = 131072;     // 32768*64
static constexpr size_t OFF_PACKA = 2490368;    // 8192 floats (32 KB pack)
static constexpr size_t OFF_PACKN = 2498560;    // 8192 floats
static constexpr size_t OFF_WDP   = 2506752;    // 32768 floats (128 KB pack)
static constexpr size_t OFF_WDB   = 2539520;    // 512 floats fused dec bias

__device__ __forceinline__ float frcp(float x) { return __builtin_amdgcn_rcpf(x); }
#if __has_builtin(__builtin_amdgcn_exp2f)
__device__ __forceinline__ float fexp2(float x) { return __builtin_amdgcn_exp2f(x); }
#else
__device__ __forceinline__ float fexp2(float x) { return exp2f(x); }
#endif
__device__ __forceinline__ unsigned bf16rne(float f) {
  unsigned u = __float_as_uint(f);
  u += 0x7fff + ((u >> 16) & 1);
  return u >> 16;
}
__device__ __forceinline__ v4f mfma16(v8s a, v8s b, v4f c) {
  return __builtin_amdgcn_mfma_f32_16x16x32_bf16(a, b, c, 0, 0, 0);
}

// Shared-rcp LSTM cell. Gates PRE-SCALED: i,f,o by log2e; g by 2*log2e.
__device__ __forceinline__ float cell_update(float iv, float fv, float gv,
                                             float ov, float& cref) {
  float ef = fexp2(-fv);
  float ei = fexp2(-iv);
  float eg = fexp2(-gv);
  float t1 = (1.f + ei) * (1.f + eg);
  float rD = frcp((1.f + ef) * t1);
  float sf = t1 * rD;
  float u  = (1.f - eg) * ((1.f + ef) * rD);
  float cn = fmaf(sf, cref, u);
  cref = cn;
  float eo = fexp2(-ov);
  float ec = fexp2(fminf(-L2E2 * cn, 60.f));
  return (1.f - ec) * frcp((1.f + eo) * (1.f + ec));
}

// pack 8 consecutive scaled floats -> hi-only RNE bf16x8 (one uint4)
__device__ __forceinline__ uint4 pack8(const float* __restrict__ p, float gs) {
  float4 w0 = *(const float4*)p;
  float4 w1 = *(const float4*)(p + 4);
  uint4 o;
  o.x = bf16rne(w0.x * gs) | (bf16rne(w0.y * gs) << 16);
  o.y = bf16rne(w0.z * gs) | (bf16rne(w0.w * gs) << 16);
  o.z = bf16rne(w1.x * gs) | (bf16rne(w1.y * gs) << 16);
  o.w = bf16rne(w1.z * gs) | (bf16rne(w1.w * gs) << 16);
  return o;
}
__device__ __forceinline__ uint4 pack8sum(const float* __restrict__ pa,
                                          const float* __restrict__ pb, float gs) {
  float4 a0 = *(const float4*)pa, a1 = *(const float4*)(pa + 4);
  float4 b0 = *(const float4*)pb, b1 = *(const float4*)(pb + 4);
  uint4 o;
  o.x = bf16rne((a0.x + b0.x) * gs) | (bf16rne((a0.y + b0.y) * gs) << 16);
  o.y = bf16rne((a0.z + b0.z) * gs) | (bf16rne((a0.w + b0.w) * gs) << 16);
  o.z = bf16rne((a1.x + b1.x) * gs) | (bf16rne((a1.y + b1.y) * gs) << 16);
  o.w = bf16rne((a1.z + b1.z) * gs) | (bf16rne((a1.w + b1.w) * gs) << 16);
  return o;
}

// ---------------------------------------------------------------------------
// Merged prep, 48 blocks x 256 (unchanged R12).
// ---------------------------------------------------------------------------
__global__ void prep_kernel(const float* __restrict__ Whh_a, const float* __restrict__ Whh_n,
                            const float* __restrict__ Wih_d, const float* __restrict__ Whh_d,
                            const float* __restrict__ bih_d, const float* __restrict__ bhh_d,
                            uint4* __restrict__ packA, uint4* __restrict__ packN,
                            uint4* __restrict__ packD, float* __restrict__ bd) {
  const int b = blockIdx.x;
  if (b < 16) {
    const int which = b >> 3;
    const float* Whh = which ? Whh_n : Whh_a;
    uint4* dst = which ? packN : packA;
    const int idx = (b & 7) * 256 + threadIdx.x;   // 0..2047
    const int lane = idx & 63, c = idx >> 6;       // c 0..31
    const int kh = c & 1, g = (c >> 1) & 3, w = c >> 3;
    const float gs = (g == 2) ? L2E2 : L2E;
    const int row = g * 64 + 16 * w + (lane & 15);
    const int kb = kh * 32 + (lane >> 4) * 8;
    dst[c * 64 + lane] = pack8(Whh + row * 64 + kb, gs);
  } else {
    const int idx = (b - 16) * 256 + threadIdx.x;  // 0..8191
    const int lane = idx & 63, c = idx >> 6;       // c 0..127
    const int kh = c & 3, i = (c >> 2) & 1, wv = c >> 3;
    const int g = wv & 3, q = wv >> 2;
    const float gs = (g == 2) ? L2E2 : L2E;
    const int ju = q * 32 + i * 16 + (lane & 15);
    const int row = g * 128 + ju;
    const int kb = kh * 32 + (lane >> 4) * 8;
    packD[c * 64 + lane] = pack8sum(Wih_d + row * 128 + kb, Whh_d + row * 128 + kb, gs);
    if (b < 18) {
      int iB = (b - 16) * 256 + threadIdx.x;       // 0..511
      float s = ((iB >> 7) == 2) ? L2E2 : L2E;
      bd[iB] = (bih_d[iB] + bhh_d[iB]) * s;
    }
  }
}

// ---------------------------------------------------------------------------
// Encoder. Blocks [0,2048) neighbour, [2048,2176) agent; 256 thr = 4 waves.
// Ping-pong h planes (halfwords, HI-ONLY): buf b at base b*1152; row
// stride 72. t-loop unrolled x2 -> literal bases. 8 MFMA/step.
// ---------------------------------------------------------------------------
__global__ __launch_bounds__(256, 4) void enc_mfma_kernel(
    const float* __restrict__ xA, const float* __restrict__ xN,
    const v8s* __restrict__ packA, const v8s* __restrict__ packN,
    const float* __restrict__ Wih_a, const float* __restrict__ bih_a, const float* __restrict__ bhh_a,
    const float* __restrict__ Wih_n, const float* __restrict__ bih_n, const float* __restrict__ bhh_n,
    float* __restrict__ outA, float* __restrict__ outN) {
  __shared__ unsigned short hph[2304];  // 2 ping-pong hi-planes
  __shared__ float xst[1600];
  const int tid = threadIdx.x, lane = tid & 63, wv = tid >> 6;
  const int nb = blockIdx.x;
  const bool isA = nb >= 2048;
  const float* xsrc = isA ? xA : xN;
  const v8s* pk = isA ? packA : packN;
  const float* Wih = isA ? Wih_a : Wih_n;
  const float* bih = isA ? bih_a : bih_n;
  const float* bhh = isA ? bhh_a : bhh_n;
  float* outp = isA ? outA : outN;
  const int s0 = (isA ? nb - 2048 : nb) * 16;

  // coalesced B-frag load (hi-only): chunk = wv*8+g*2+kh
  v8s B[4][2];
#pragma unroll
  for (int g = 0; g < 4; ++g)
#pragma unroll
    for (int kh = 0; kh < 2; ++kh)
      B[g][kh] = pk[(wv * 8 + g * 2 + kh) * 64 + lane];

  const int jc = lane & 15, qc = lane >> 4;  // C roles: unit col, seq quad
  float wi0[4], wi1[4], bs[4];
#pragma unroll
  for (int g = 0; g < 4; ++g) {
    const float gs = (g == 2) ? L2E2 : L2E;
    int n = g * 64 + 16 * wv + jc;
    wi0[g] = Wih[n * 2 + 0] * gs;
    wi1[g] = Wih[n * 2 + 1] * gs;
    bs[g] = (bih[n] + bhh[n]) * gs;
  }

  // stage x (1600 floats) + zero buf0 (576 dwords)
  {
    const float4* xb = (const float4*)(xsrc + (size_t)s0 * 100);
    for (int i = tid; i < 400; i += 256) ((float4*)xst)[i] = xb[i];
    for (int i = tid; i < 576; i += 256) ((unsigned*)hph)[i] = 0;
  }
  __syncthreads();

  const int ms = lane & 15, ks = lane >> 4;  // A roles: seq row, k-quad
  float cst[4] = {0.f, 0.f, 0.f, 0.f};
  float h[4];

  auto enc_step = [&](int t, int rb, int wb) {
    // acc init: exact fp32 input projection + bias (scaled)
    v4f a4[4];
#pragma unroll
    for (int r = 0; r < 4; ++r) {
      v2f xv = *(const __shared__ v2f*)&xst[(qc * 4 + r) * 100 + 2 * t];
#pragma unroll
      for (int g = 0; g < 4; ++g)
        a4[g][r] = fmaf(wi1[g], xv.y, fmaf(wi0[g], xv.x, bs[g]));
    }

    // h @ Whh^T, A hi-only: 8 MFMA
#pragma unroll
    for (int kh = 0; kh < 2; ++kh) {
      v8s Ahi = *(const __shared__ v8s*)&hph[rb + ms * 72 + kh * 32 + ks * 8];
#pragma unroll
      for (int g = 0; g < 4; ++g)
        a4[g] = mfma16(Ahi, B[g][kh], a4[g]);
    }

    // pointwise + RNE bf16 h-store into the OTHER buffer
#pragma unroll
    for (int r = 0; r < 4; ++r) {
      h[r] = cell_update(a4[0][r], a4[1][r], a4[2][r], a4[3][r], cst[r]);
      hph[wb + (qc * 4 + r) * 72 + 16 * wv + jc] =
          (unsigned short)bf16rne(h[r]);
    }
    __syncthreads();
  };

  for (int t2 = 0; t2 < T_SEQ; t2 += 2) {
    enc_step(t2 + 0, 0, 1152);
    enc_step(t2 + 1, 1152, 0);
  }

#pragma unroll
  for (int r = 0; r < 4; ++r)
    outp[(size_t)(s0 + qc * 4 + r) * 64 + 16 * wv + jc] = h[r];
}

// ---------------------------------------------------------------------------
// Decoder v7. 256 blocks x 1024 thr (16 waves), 8 seqs/block.
// Wave wv: gate g = wv&3, unit-quarter q = wv>>2 -> 2 col-tiles of 16
// units; A hi-only -> 8 MFMA/step. Preds in LDS, one store.
// ---------------------------------------------------------------------------
__global__ __launch_bounds__(1024, 4) void dec_mfma_kernel(
    const v8s* __restrict__ pkd, const float* __restrict__ bd,
    const float* __restrict__ aemb, const float* __restrict__ nenc,
    const int* __restrict__ cnts, const float* __restrict__ Wpos,
    const float* __restrict__ bpos, float* __restrict__ out) {
  __shared__ unsigned short hph[2176];   // hi-only, row stride 136
  __shared__ float gbuf[4][8][132];
  __shared__ float ppart[16][2];
  __shared__ float pbuf[480];
  const int tid = threadIdx.x, lane = tid & 63, wv = tid >> 6;  // wv 0..15
  const int jc = lane & 15, qc = lane >> 4;
  const int g = wv & 3, q = wv >> 2;
  const int s0 = blockIdx.x * 8;

  // coalesced B-frag load: chunk = wv*8+i*4+kh
  v8s B[2][4];
  float bs[2];
#pragma unroll
  for (int i = 0; i < 2; ++i) {
#pragma unroll
    for (int kh = 0; kh < 4; ++kh)
      B[i][kh] = pkd[(wv * 8 + i * 4 + kh) * 64 + lane];
    bs[i] = bd[g * 128 + q * 32 + i * 16 + jc];
  }

  // cell-phase constants: seq sq = wv>>1, unit cu = (wv&1)*64 + lane
  const int cu = (wv & 1) * 64 + lane;
  const int sq = wv >> 1;
  const float wp0 = Wpos[cu], wp1 = Wpos[128 + cu];
  const float bp0 = bpos[0], bp1 = bpos[1];

  // stage h0 rows 0..7 (fused hmax, batched loads) + zero rows 8..15
  for (int i = tid; i < 2048; i += 1024) {
    int row = i >> 7, unit = i & 127;
    unsigned hiw = 0;
    if (row < 8) {
      float v;
      if (unit < 64) {
        v = aemb[(size_t)(s0 + row) * 64 + unit];
      } else {
        int cnt = cnts[s0 + row];
        float m = -1e30f;
#pragma unroll
        for (int n = 0; n < NMAX; ++n) {
          float val = nenc[((size_t)((s0 + row) * NMAX + n)) * 64 + (unit - 64)];
          m = (n < cnt) ? fmaxf(m, val) : m;
        }
        v = (cnt > 0) ? m : 0.f;
      }
      hiw = bf16rne(v);
    }
    hph[row * 136 + unit] = (unsigned short)hiw;
  }
  float cst = 0.f;
  __syncthreads();

  for (int t = 0; t < PRED_STEPS; ++t) {
    v4f acc[2];
#pragma unroll
    for (int i = 0; i < 2; ++i)
      acc[i] = (v4f){bs[i], bs[i], bs[i], bs[i]};
#pragma unroll
    for (int kh = 0; kh < 4; ++kh) {
      v8s Ahi = *(const __shared__ v8s*)&hph[jc * 136 + kh * 32 + qc * 8];
#pragma unroll
      for (int i = 0; i < 2; ++i)
        acc[i] = mfma16(Ahi, B[i][kh], acc[i]);
    }

    // publish gates (rows 0..7 -> lanes qc<2)
    if (qc < 2) {
#pragma unroll
      for (int i = 0; i < 2; ++i)
#pragma unroll
        for (int r = 0; r < 4; ++r)
          gbuf[g][qc * 4 + r][q * 32 + i * 16 + jc] = acc[i][r];
    }
    __syncthreads();  // barrier1: gates visible, A-reads complete

    // cell phase: 1 cell per thread (seq sq, unit cu)
    float gI = gbuf[0][sq][cu];
    float gF = gbuf[1][sq][cu];
    float gG = gbuf[2][sq][cu];
    float gO = gbuf[3][sq][cu];
    float h = cell_update(gI, gF, gG, gO, cst);

    hph[sq * 136 + cu] = (unsigned short)bf16rne(h);

    // pred partials: wave covers 64 of 128 units of seq sq
    float p0 = h * wp0;
    float p1 = h * wp1;
#pragma unroll
    for (int off = 32; off > 0; off >>= 1) {
      p0 += __shfl_xor(p0, off, 64);
      p1 += __shfl_xor(p1, off, 64);
    }
    if (lane == 0) { ppart[wv][0] = p0; ppart[wv][1] = p1; }
    __syncthreads();  // barrier2: h plane + ppart visible

    if (tid < 16) {
      int s = tid >> 1, cc = tid & 1;
      pbuf[s * 60 + t * 2 + cc] =
          ppart[2 * s][cc] + ppart[2 * s + 1][cc] + (cc ? bp1 : bp0);
    }
  }
  __syncthreads();
  if (tid < 480) out[(size_t)s0 * 60 + tid] = pbuf[tid];
}

extern "C" void kernel_launch(void* const* d_in, const int* in_sizes, int n_in,
                              void* d_out, int out_size, void* d_ws, size_t ws_size,
                              hipStream_t stream) {
  (void)in_sizes; (void)n_in; (void)out_size; (void)ws_size;
  const float* xA    = (const float*)d_in[0];
  const float* xN    = (const float*)d_in[1];
  const int*   cnts  = (const int*)d_in[2];
  const float* Wih_a = (const float*)d_in[3];
  const float* Whh_a = (const float*)d_in[4];
  const float* bih_a = (const float*)d_in[5];
  const float* bhh_a = (const float*)d_in[6];
  const float* Wih_n = (const float*)d_in[7];
  const float* Whh_n = (const float*)d_in[8];
  const float* bih_n = (const float*)d_in[9];
  const float* bhh_n = (const float*)d_in[10];
  const float* Wih_d = (const float*)d_in[11];
  const float* Whh_d = (const float*)d_in[12];
  const float* bih_d = (const float*)d_in[13];
  const float* bhh_d = (const float*)d_in[14];
  const float* Wpos  = (const float*)d_in[15];
  const float* bpos  = (const float*)d_in[16];
  float* out = (float*)d_out;
  float* wsf = (float*)d_ws;

  prep_kernel<<<48, 256, 0, stream>>>(Whh_a, Whh_n, Wih_d, Whh_d, bih_d, bhh_d,
                                      (uint4*)(wsf + OFF_PACKA),
                                      (uint4*)(wsf + OFF_PACKN),
                                      (uint4*)(wsf + OFF_WDP), wsf + OFF_WDB);
  enc_mfma_kernel<<<2176, 256, 0, stream>>>(
      xA, xN,
      (const v8s*)(wsf + OFF_PACKA), (const v8s*)(wsf + OFF_PACKN),
      Wih_a, bih_a, bhh_a, Wih_n, bih_n, bhh_n,
      wsf + OFF_AEMB, wsf + OFF_NENC);
  dec_mfma_kernel<<<256, 1024, 0, stream>>>(
      (const v8s*)(wsf + OFF_WDP), wsf + OFF_WDB,
      wsf + OFF_AEMB, wsf + OFF_NENC, cnts,
      Wpos, bpos, out);
}